// Round 3
// baseline (719.912 us; speedup 1.0000x reference)
//
#include <hip/hip_runtime.h>
#include <hip/hip_bf16.h>

#define NN 1024
#define DD 128
#define HH 128

// ws layout (floats): [0..127]=u (Wr^T w3), [128]=c (bh.w1+bt.w2+br.w3+wt_b),
//                     [160..287]=v (Wh^T w1 + Wt^T w2), [320..1343]=node_part+c
__global__ void prep_kernel(const float* __restrict__ Wh,
                            const float* __restrict__ bh,
                            const float* __restrict__ Wt,
                            const float* __restrict__ bt,
                            const float* __restrict__ Wr,
                            const float* __restrict__ br,
                            const float* __restrict__ wt_w,
                            const float* __restrict__ wt_b,
                            float* __restrict__ ws) {
    __shared__ float w[3 * HH];
    __shared__ float ps[2];
    const int t = threadIdx.x;  // 128 threads
    for (int idx = t; idx < 3 * HH; idx += 128) w[idx] = wt_w[idx];
    __syncthreads();
    float u = 0.f, v = 0.f;
    for (int h = 0; h < HH; ++h) {
        u = fmaf(Wr[h * DD + t], w[2 * HH + h], u);
        v = fmaf(Wh[h * DD + t], w[h], v);
        v = fmaf(Wt[h * DD + t], w[HH + h], v);
    }
    ws[t] = u;
    ws[160 + t] = v;
    float p = bh[t] * w[t] + bt[t] * w[HH + t] + br[t] * w[2 * HH + t];
    #pragma unroll
    for (int m = 1; m < 64; m <<= 1) p += __shfl_xor(p, m, 64);
    if ((t & 63) == 0) ps[t >> 6] = p;
    __syncthreads();
    if (t == 0) ws[128] = ps[0] + ps[1] + wt_b[0];
}

__global__ void nodepart_kernel(const float* __restrict__ node_feat,
                                float* __restrict__ ws) {
    __shared__ float v[DD];
    const int t = threadIdx.x;  // 256 threads, 4 blocks
    if (t < DD) v[t] = ws[160 + t];
    __syncthreads();
    const float c = ws[128];
    const int j = blockIdx.x * 256 + t;
    const float4* p = (const float4*)(node_feat + (size_t)j * DD);
    float acc = 0.f;
    #pragma unroll
    for (int it = 0; it < 32; ++it) {
        float4 q = p[it];
        const int d0 = it * 4;
        acc = fmaf(q.x, v[d0 + 0], acc);
        acc = fmaf(q.y, v[d0 + 1], acc);
        acc = fmaf(q.z, v[d0 + 2], acc);
        acc = fmaf(q.w, v[d0 + 3], acc);
    }
    ws[320 + j] = acc + c;
}

__global__ __launch_bounds__(256, 4) void energy_softmax_kernel(
    const float* __restrict__ edge,
    const float* __restrict__ ws,
    float* __restrict__ out) {
    __shared__ float e[NN];
    __shared__ float red[8];
    const int t = threadIdx.x;
    const int i = blockIdx.x;
    const int lane = t & 63;
    const int wave = t >> 6;
    const int sub = lane & 31;   // which float4 chunk (32 per 128-f32 row)
    const int jw = lane >> 5;    // which of 2 j's this wave handles per iter

    // per-lane fragment of u: u[sub*4 .. sub*4+4)
    float uf[4];
    {
        const float* up = ws + sub * 4;
        #pragma unroll
        for (int k = 0; k < 4; ++k) uf[k] = up[k];
    }

    // one i-row of edge_feat: 1024 j-rows of 512 B each = 32 float4 per j
    const float4* row = (const float4*)(edge + (size_t)i * (NN * DD));
    for (int it = 0; it < 128; ++it) {
        const int j = it * 8 + wave * 2 + jw;
        // wave reads contiguous 1 KB: lane l -> l*16 B within a 2-row chunk
        float4 q = row[j * 32 + sub];
        float acc;
        acc = q.x * uf[0];
        acc = fmaf(q.y, uf[1], acc);
        acc = fmaf(q.z, uf[2], acc);
        acc = fmaf(q.w, uf[3], acc);
        // reduce across the 32 lanes sharing this j
        acc += __shfl_xor(acc, 1, 64);
        acc += __shfl_xor(acc, 2, 64);
        acc += __shfl_xor(acc, 4, 64);
        acc += __shfl_xor(acc, 8, 64);
        acc += __shfl_xor(acc, 16, 64);
        if (sub == 0) e[j] = acc;
    }
    __syncthreads();

    const float* np = ws + 320;
    float vals[4];
    float m = -1e30f;
    #pragma unroll
    for (int k = 0; k < 4; ++k) {
        const int j = t + k * 256;
        const float val = e[j] + np[j];   // np includes all scalar constants
        vals[k] = val;
        m = fmaxf(m, val);
    }
    #pragma unroll
    for (int msk = 1; msk < 64; msk <<= 1) m = fmaxf(m, __shfl_xor(m, msk, 64));
    if (lane == 0) red[wave] = m;
    __syncthreads();
    m = fmaxf(fmaxf(red[0], red[1]), fmaxf(red[2], red[3]));

    float s = 0.f;
    #pragma unroll
    for (int k = 0; k < 4; ++k) {
        const float ev = __expf(vals[k] - m);
        vals[k] = ev;
        s += ev;
    }
    #pragma unroll
    for (int msk = 1; msk < 64; msk <<= 1) s += __shfl_xor(s, msk, 64);
    if (lane == 0) red[4 + wave] = s;
    __syncthreads();
    s = (red[4] + red[5]) + (red[6] + red[7]);
    const float inv = 1.0f / s;

    float* orow = out + (size_t)i * NN;
    #pragma unroll
    for (int k = 0; k < 4; ++k) {
        const int j = t + k * 256;
        orow[j] = vals[k] * inv;   // f32 output, coalesced across threads
    }
}

extern "C" void kernel_launch(void* const* d_in, const int* in_sizes, int n_in,
                              void* d_out, int out_size, void* d_ws, size_t ws_size,
                              hipStream_t stream) {
    const float* node_feat = (const float*)d_in[0];
    const float* edge_feat = (const float*)d_in[1];
    // d_in[2] = mask (int32, all zeros, unused by the reference)
    const float* Wh   = (const float*)d_in[3];
    const float* bh   = (const float*)d_in[4];
    const float* Wt   = (const float*)d_in[5];
    const float* bt   = (const float*)d_in[6];
    const float* Wr   = (const float*)d_in[7];
    const float* br   = (const float*)d_in[8];
    const float* wt_w = (const float*)d_in[9];
    const float* wt_b = (const float*)d_in[10];
    float* ws = (float*)d_ws;
    float* out = (float*)d_out;

    prep_kernel<<<1, 128, 0, stream>>>(Wh, bh, Wt, bt, Wr, br, wt_w, wt_b, ws);
    nodepart_kernel<<<4, 256, 0, stream>>>(node_feat, ws);
    energy_softmax_kernel<<<NN, 256, 0, stream>>>(edge_feat, ws, out);
}